// Round 10
// baseline (221.572 us; speedup 1.0000x reference)
//
#include <hip/hip_runtime.h>

typedef __attribute__((ext_vector_type(8))) short bf16x8;
typedef __attribute__((ext_vector_type(4))) float f32x4;
typedef __attribute__((ext_vector_type(2))) unsigned int u32x2;
typedef __attribute__((ext_vector_type(8))) unsigned short ushort8v;

__device__ __forceinline__ unsigned short f2bf(float f) {
  unsigned int u = __float_as_uint(f);
  u += 0x7fffu + ((u >> 16) & 1u);  // round-to-nearest-even
  return (unsigned short)(u >> 16);
}

__device__ __forceinline__ void gload_lds16(const unsigned short* g, unsigned short* l) {
  __builtin_amdgcn_global_load_lds(
      (const __attribute__((address_space(1))) unsigned int*)g,
      (__attribute__((address_space(3))) unsigned int*)l,
      16, 0, 0);
}

// ---------------- fused fp32 -> bf16 convert: 8 elems/thread/iter, 16B stores ----------------
__global__ void cvt_all(const float* __restrict__ x, const float* __restrict__ wq,
                        const float* __restrict__ wp, unsigned short* __restrict__ dst) {
  const int n1 = 4096 * 1024 / 8, n2 = 3072 * 1024 / 8, n3 = 1024 * 1024 / 8;
  int stride = gridDim.x * blockDim.x;
  for (int i = blockIdx.x * blockDim.x + threadIdx.x; i < n1 + n2 + n3; i += stride) {
    const float* s; int j;
    if (i < n1)           { s = x;  j = i; }
    else if (i < n1 + n2) { s = wq; j = i - n1; }
    else                  { s = wp; j = i - n1 - n2; }
    float4 a = ((const float4*)s)[j * 2];
    float4 b = ((const float4*)s)[j * 2 + 1];
    ushort8v o;
    o[0] = f2bf(a.x); o[1] = f2bf(a.y); o[2] = f2bf(a.z); o[3] = f2bf(a.w);
    o[4] = f2bf(b.x); o[5] = f2bf(b.y); o[6] = f2bf(b.z); o[7] = f2bf(b.w);
    ((ushort8v*)dst)[i] = o;
  }
}

// ---------------- 128x128 gemm_bt (round-3 structure + conflict-free chunk-XOR) ----------------
__device__ __forceinline__ void gemm128_bt(const unsigned short* __restrict__ A,
                                           const unsigned short* __restrict__ Bt,
                                           unsigned short* As, unsigned short* Bs,
                                           int tm, int tn, f32x4 acc[4][4]) {
  const int K = 1024;
  int tid = threadIdx.x;
  int w = tid >> 6, l = tid & 63;
  int wr = w >> 1, wc = w & 1;
  int g = l >> 4, c = l & 15;

  int srow = w * 32 + (l >> 2);
  int skoff = (((l & 3) ^ ((srow >> 1) & 3)) * 8);  // pre-swizzled source k-offset
  const unsigned short* gA = A + (size_t)(tm * 128 + srow) * K + skoff;
  const unsigned short* gB = Bt + (size_t)(tn * 128 + srow) * K + skoff;
  unsigned short* lA = As + (w * 32) * 32;  // wave-uniform LDS base (linear dest)
  unsigned short* lB = Bs + (w * 32) * 32;

  int rx = (c >> 1) & 3;  // f(row) for all fragment rows (row = base16 + c)
  int arow = wr * 64 + c;
  int brow = wc * 64 + c;

  for (int k0 = 0; k0 < K; k0 += 32) {
    gload_lds16(gA, lA);
    gload_lds16(gA + 16 * K, lA + 16 * 32);  // row+16: same (r>>1)&3 -> same skoff
    gload_lds16(gB, lB);
    gload_lds16(gB + 16 * K, lB + 16 * 32);
    gA += 32; gB += 32;
    __syncthreads();
    bf16x8 af[4], bfr[4];
#pragma unroll
    for (int mi = 0; mi < 4; ++mi)
      af[mi] = *(const bf16x8*)((const char*)As + (arow + mi * 16) * 64 + ((g ^ rx) << 4));
#pragma unroll
    for (int ni = 0; ni < 4; ++ni)
      bfr[ni] = *(const bf16x8*)((const char*)Bs + (brow + ni * 16) * 64 + ((g ^ rx) << 4));
#pragma unroll
    for (int mi = 0; mi < 4; ++mi)
#pragma unroll
      for (int ni = 0; ni < 4; ++ni)
        acc[mi][ni] = __builtin_amdgcn_mfma_f32_16x16x32_bf16(af[mi], bfr[ni], acc[mi][ni], 0, 0, 0);
    __syncthreads();
  }
}

// ---------------- QKV projection: scatter into Q (scaled), K, V^T ----------------
__global__ __launch_bounds__(256) void qkv_gemm(const unsigned short* __restrict__ xb,
                                                const unsigned short* __restrict__ wb,
                                                unsigned short* __restrict__ Qp,
                                                unsigned short* __restrict__ Kp,
                                                unsigned short* __restrict__ Vt) {
  __shared__ unsigned short As[128 * 32];
  __shared__ unsigned short Bs[128 * 32];
  f32x4 acc[4][4];
#pragma unroll
  for (int i = 0; i < 4; ++i)
#pragma unroll
    for (int j = 0; j < 4; ++j) acc[i][j] = f32x4{0.f, 0.f, 0.f, 0.f};
  int id = (blockIdx.x & 7) * 96 + (blockIdx.x >> 3);  // bijective (768 % 8 == 0)
  int tm = id / 24, tn = id % 24;
  gemm128_bt(xb, wb, As, Bs, tm, tn, acc);

  int tid = threadIdx.x;
  int w = tid >> 6, l = tid & 63;
  int wr = w >> 1, wc = w & 1;
  int g = l >> 4, c = l & 15;
  const float QSCALE = 0.125f * 1.44269504088896f;  // hd^-0.5 * log2(e)
#pragma unroll
  for (int mi = 0; mi < 4; ++mi)
#pragma unroll
    for (int ni = 0; ni < 4; ++ni)
#pragma unroll
      for (int r = 0; r < 4; ++r) {
        int row = tm * 128 + wr * 64 + mi * 16 + g * 4 + r;   // 0..4095
        int col = tn * 128 + wc * 64 + ni * 16 + c;           // 0..3071
        int b = row >> 11, seq = row & 2047;
        int t = col >> 10;
        int h = (col >> 6) & 15, d = col & 63;
        size_t bh = (size_t)b * 16 + h;
        float v = acc[mi][ni][r];
        if (t == 0)      Qp[(bh * 2048 + seq) * 64 + d] = f2bf(v * QSCALE);
        else if (t == 1) Kp[(bh * 2048 + seq) * 64 + d] = f2bf(v);
        else             Vt[(bh * 64 + d) * 2048 + seq] = f2bf(v);           // transposed V
      }
}

// ---------------- block-causal flash attention: swapped QK^T, in-register P, V from L2 ----------
// mfma(K,Q): P[q=c][k=nf*16+4g+r] lane-local -> cvt_pk -> x16-MFMA A-frags, no LDS round-trip.
// V is NOT staged (guide m169: L2-resident V-staging is pure overhead): the x16 B-frag is 4
// seq-contiguous bf16 at fixed d = one 8B global load from Vt [d][seq]; 4bh/XCD -> 2MB in L2.
// 16 V loads issued at iter top hide under QK^T+exp2. K stays in LDS (consumed immediately).
__global__ __launch_bounds__(256, 4) void attn_fa(const unsigned short* __restrict__ Qp,
                                                  const unsigned short* __restrict__ Kp,
                                                  const unsigned short* __restrict__ Vt,
                                                  unsigned short* __restrict__ attn) {
  __shared__ unsigned short Ks[2][4096];   // [buf][64 rows x 64 elems], swizzled
  int tid = threadIdx.x;
  int w = tid >> 6, l = tid & 63;
  int g = l >> 4, c = l & 15;

  int idx = blockIdx.x;
  int pos = idx >> 3;                    // 0..127
  int qb = 31 - (pos >> 2);              // heavy blocks dispatch first
  int bh = (idx & 7) + 8 * (pos & 3);    // 4 bh per XCD slot (K/V L2 locality)

  const unsigned short* Qbh = Qp + (size_t)bh * 2048 * 64;
  const unsigned short* Kbh = Kp + (size_t)bh * 2048 * 64;
  const unsigned short* Vbh = Vt + (size_t)bh * 64 * 2048;

  int rowA, colA, rowB, colB;
  { int L = tid * 16;         int P = L ^ (((L >> 7) & 7) << 4); rowA = P >> 7; colA = (P & 127) >> 1; }
  { int L = (tid + 256) * 16; int P = L ^ (((L >> 7) & 7) << 4); rowB = P >> 7; colB = (P & 127) >> 1; }
  const unsigned short* gKA = Kbh + rowA * 64 + colA;            // + kb*4096
  const unsigned short* gKB = Kbh + rowB * 64 + colB;

#define STAGE(buf, kb)                                              \
  do {                                                              \
    gload_lds16(gKA + (kb) * 4096, &Ks[(buf)][w * 512]);            \
    gload_lds16(gKB + (kb) * 4096, &Ks[(buf)][w * 512 + 2048]);     \
  } while (0)

  bf16x8 qf[2];
  {
    size_t qrow = (size_t)qb * 64 + w * 16 + c;
    qf[0] = *(const bf16x8*)(Qbh + qrow * 64 + 8 * g);
    qf[1] = *(const bf16x8*)(Qbh + qrow * 64 + 32 + 8 * g);
  }
  // per-lane V base: d-row (df adds 16 rows), seq offset 4g
  const unsigned short* Vlane = Vbh + (size_t)c * 2048 + 4 * g;

  float lp4[4] = {0.f, 0.f, 0.f, 0.f};  // per-lane partial denominators (all for q-row c)
  f32x4 o[4];
#pragma unroll
  for (int df = 0; df < 4; ++df) o[df] = f32x4{0.f, 0.f, 0.f, 0.f};

  int xorv = c & 7;

  int cur = 0;
  STAGE(0, 0);
  __syncthreads();
  for (int kb = 0; kb <= qb; ++kb) {
    if (kb < qb) STAGE(1 - cur, kb + 1);

    // V fragments straight from global (L2-hit); consumed only at PV below
    u32x2 vf[4][4];
#pragma unroll
    for (int df = 0; df < 4; ++df)
#pragma unroll
      for (int ks = 0; ks < 4; ++ks)
        vf[df][ks] = *(const u32x2*)(Vlane + (size_t)df * 16 * 2048 + kb * 64 + ks * 16);

    const char* Kb = (const char*)&Ks[cur][0];
    bf16x8 kf[8];
#pragma unroll
    for (int nf = 0; nf < 4; ++nf) {
      int r = nf * 16 + c;
#pragma unroll
      for (int ks = 0; ks < 2; ++ks)
        kf[nf * 2 + ks] = *(const bf16x8*)(Kb + r * 128 + (((ks * 4 + g) ^ xorv) * 16));
    }
    // swapped QK^T: s4[nf][r] = S[q=c][k = nf*16 + 4g + r]
    f32x4 s4[4];
#pragma unroll
    for (int nf = 0; nf < 4; ++nf) {
      s4[nf] = f32x4{0.f, 0.f, 0.f, 0.f};
      s4[nf] = __builtin_amdgcn_mfma_f32_16x16x32_bf16(kf[nf * 2 + 0], qf[0], s4[nf], 0, 0, 0);
      s4[nf] = __builtin_amdgcn_mfma_f32_16x16x32_bf16(kf[nf * 2 + 1], qf[1], s4[nf], 0, 0, 0);
    }
    // exp2 + in-register pack to PV A-fragments
    u32x2 pa[4];
#pragma unroll
    for (int nf = 0; nf < 4; ++nf) {
      float p0 = __builtin_amdgcn_exp2f(s4[nf][0]);
      float p1 = __builtin_amdgcn_exp2f(s4[nf][1]);
      float p2 = __builtin_amdgcn_exp2f(s4[nf][2]);
      float p3 = __builtin_amdgcn_exp2f(s4[nf][3]);
      lp4[nf] += (p0 + p1) + (p2 + p3);
      unsigned int w0, w1;
      asm("v_cvt_pk_bf16_f32 %0, %1, %2" : "=v"(w0) : "v"(p0), "v"(p1));
      asm("v_cvt_pk_bf16_f32 %0, %1, %2" : "=v"(w1) : "v"(p2), "v"(p3));
      pa[nf][0] = w0; pa[nf][1] = w1;
    }
    // PV: O[q][d] += P[q][k] V[k][d] via 16x16x16
#pragma unroll
    for (int df = 0; df < 4; ++df)
#pragma unroll
      for (int ks = 0; ks < 4; ++ks)
        asm("v_mfma_f32_16x16x16_bf16 %0, %1, %2, %0"
            : "+v"(o[df]) : "v"(pa[ks]), "v"(vf[df][ks]));
    __syncthreads();
    cur ^= 1;
  }
#undef STAGE

  // denominator: all partials in this lane belong to q-row c
  float lp = (lp4[0] + lp4[1]) + (lp4[2] + lp4[3]);
  lp += __shfl_xor(lp, 16);
  lp += __shfl_xor(lp, 32);
  float inv[4];
#pragma unroll
  for (int r = 0; r < 4; ++r) inv[r] = __builtin_amdgcn_rcpf(__shfl(lp, g * 4 + r));

  int b = bh >> 4, h = bh & 15;
#pragma unroll
  for (int df = 0; df < 4; ++df)
#pragma unroll
    for (int r = 0; r < 4; ++r) {
      int row = qb * 64 + w * 16 + g * 4 + r;
      int colc = h * 64 + df * 16 + c;
      attn[((size_t)b * 2048 + row) * 1024 + colc] = f2bf(o[df][r] * inv[r]);
    }
}

// ---------------- output projection + bias (fp32 out) ----------------
__global__ __launch_bounds__(256) void proj_gemm(const unsigned short* __restrict__ attn,
                                                 const unsigned short* __restrict__ wpb,
                                                 const float* __restrict__ bias,
                                                 float* __restrict__ out) {
  __shared__ unsigned short As[128 * 32];
  __shared__ unsigned short Bs[128 * 32];
  f32x4 acc[4][4];
#pragma unroll
  for (int i = 0; i < 4; ++i)
#pragma unroll
    for (int j = 0; j < 4; ++j) acc[i][j] = f32x4{0.f, 0.f, 0.f, 0.f};
  int id = (blockIdx.x & 7) * 32 + (blockIdx.x >> 3);  // bijective (256 % 8 == 0)
  int tm = id / 8, tn = id % 8;
  gemm128_bt(attn, wpb, As, Bs, tm, tn, acc);

  int tid = threadIdx.x;
  int w = tid >> 6, l = tid & 63;
  int wr = w >> 1, wc = w & 1;
  int g = l >> 4, c = l & 15;
#pragma unroll
  for (int mi = 0; mi < 4; ++mi)
#pragma unroll
    for (int ni = 0; ni < 4; ++ni)
#pragma unroll
      for (int r = 0; r < 4; ++r) {
        int row = tm * 128 + wr * 64 + mi * 16 + g * 4 + r;
        int col = tn * 128 + wc * 64 + ni * 16 + c;
        out[(size_t)row * 1024 + col] = acc[mi][ni][r] + bias[col];
      }
}

extern "C" void kernel_launch(void* const* d_in, const int* in_sizes, int n_in,
                              void* d_out, int out_size, void* d_ws, size_t ws_size,
                              hipStream_t stream) {
  (void)in_sizes; (void)n_in; (void)out_size; (void)ws_size;
  const float* x      = (const float*)d_in[0];  // [2,2048,1024]
  const float* w_qkv  = (const float*)d_in[1];  // [3072,1024]
  const float* w_proj = (const float*)d_in[2];  // [1024,1024]
  const float* b_proj = (const float*)d_in[3];  // [1024]
  float* out = (float*)d_out;

  unsigned short* xb    = (unsigned short*)d_ws;          // 4096*1024
  unsigned short* wqkvb = xb + 4096 * 1024;               // 3072*1024
  unsigned short* wpb   = wqkvb + 3072 * 1024;            // 1024*1024
  unsigned short* Qp    = wpb + 1024 * 1024;              // 32*2048*64
  unsigned short* Kp    = Qp + 32 * 2048 * 64;            // 32*2048*64
  unsigned short* Vt    = Kp + 32 * 2048 * 64;            // 32*64*2048
  unsigned short* attn  = Vt + 32 * 64 * 2048;            // 4096*1024

  cvt_all<<<1024, 256, 0, stream>>>(x, w_qkv, w_proj, xb);
  qkv_gemm<<<768, 256, 0, stream>>>(xb, wqkvb, Qp, Kp, Vt);
  attn_fa<<<1024, 256, 0, stream>>>(Qp, Kp, Vt, attn);
  proj_gemm<<<256, 256, 0, stream>>>(attn, wpb, b_proj, out);
}

// Round 11
// 122.459 us; speedup vs baseline: 1.8094x; 1.8094x over previous
//
#include <hip/hip_runtime.h>

typedef __attribute__((ext_vector_type(8))) short bf16x8;
typedef __attribute__((ext_vector_type(4))) float f32x4;
typedef __attribute__((ext_vector_type(2))) unsigned int u32x2;
typedef __attribute__((ext_vector_type(8))) unsigned short ushort8v;

__device__ __forceinline__ unsigned short f2bf(float f) {
  unsigned int u = __float_as_uint(f);
  u += 0x7fffu + ((u >> 16) & 1u);  // round-to-nearest-even
  return (unsigned short)(u >> 16);
}

__device__ __forceinline__ void gload_lds16(const unsigned short* g, unsigned short* l) {
  __builtin_amdgcn_global_load_lds(
      (const __attribute__((address_space(1))) unsigned int*)g,
      (__attribute__((address_space(3))) unsigned int*)l,
      16, 0, 0);
}

// ---------------- fused fp32 -> bf16 convert: 8 elems/thread/iter, 16B stores ----------------
__global__ void cvt_all(const float* __restrict__ x, const float* __restrict__ wq,
                        const float* __restrict__ wp, unsigned short* __restrict__ dst) {
  const int n1 = 4096 * 1024 / 8, n2 = 3072 * 1024 / 8, n3 = 1024 * 1024 / 8;
  int stride = gridDim.x * blockDim.x;
  for (int i = blockIdx.x * blockDim.x + threadIdx.x; i < n1 + n2 + n3; i += stride) {
    const float* s; int j;
    if (i < n1)           { s = x;  j = i; }
    else if (i < n1 + n2) { s = wq; j = i - n1; }
    else                  { s = wp; j = i - n1 - n2; }
    float4 a = ((const float4*)s)[j * 2];
    float4 b = ((const float4*)s)[j * 2 + 1];
    ushort8v o;
    o[0] = f2bf(a.x); o[1] = f2bf(a.y); o[2] = f2bf(a.z); o[3] = f2bf(a.w);
    o[4] = f2bf(b.x); o[5] = f2bf(b.y); o[6] = f2bf(b.z); o[7] = f2bf(b.w);
    ((ushort8v*)dst)[i] = o;
  }
}

// ---------------- 128x128 gemm_bt (round-3 structure + conflict-free chunk-XOR) ----------------
__device__ __forceinline__ void gemm128_bt(const unsigned short* __restrict__ A,
                                           const unsigned short* __restrict__ Bt,
                                           unsigned short* As, unsigned short* Bs,
                                           int tm, int tn, f32x4 acc[4][4]) {
  const int K = 1024;
  int tid = threadIdx.x;
  int w = tid >> 6, l = tid & 63;
  int wr = w >> 1, wc = w & 1;
  int g = l >> 4, c = l & 15;

  int srow = w * 32 + (l >> 2);
  int skoff = (((l & 3) ^ ((srow >> 1) & 3)) * 8);  // pre-swizzled source k-offset
  const unsigned short* gA = A + (size_t)(tm * 128 + srow) * K + skoff;
  const unsigned short* gB = Bt + (size_t)(tn * 128 + srow) * K + skoff;
  unsigned short* lA = As + (w * 32) * 32;  // wave-uniform LDS base (linear dest)
  unsigned short* lB = Bs + (w * 32) * 32;

  int rx = (c >> 1) & 3;  // f(row) for all fragment rows (row = base16 + c)
  int arow = wr * 64 + c;
  int brow = wc * 64 + c;

  for (int k0 = 0; k0 < K; k0 += 32) {
    gload_lds16(gA, lA);
    gload_lds16(gA + 16 * K, lA + 16 * 32);  // row+16: same (r>>1)&3 -> same skoff
    gload_lds16(gB, lB);
    gload_lds16(gB + 16 * K, lB + 16 * 32);
    gA += 32; gB += 32;
    __syncthreads();
    bf16x8 af[4], bfr[4];
#pragma unroll
    for (int mi = 0; mi < 4; ++mi)
      af[mi] = *(const bf16x8*)((const char*)As + (arow + mi * 16) * 64 + ((g ^ rx) << 4));
#pragma unroll
    for (int ni = 0; ni < 4; ++ni)
      bfr[ni] = *(const bf16x8*)((const char*)Bs + (brow + ni * 16) * 64 + ((g ^ rx) << 4));
#pragma unroll
    for (int mi = 0; mi < 4; ++mi)
#pragma unroll
      for (int ni = 0; ni < 4; ++ni)
        acc[mi][ni] = __builtin_amdgcn_mfma_f32_16x16x32_bf16(af[mi], bfr[ni], acc[mi][ni], 0, 0, 0);
    __syncthreads();
  }
}

// ---------------- QKV projection: scatter into Q (scaled), K, V^T ----------------
__global__ __launch_bounds__(256) void qkv_gemm(const unsigned short* __restrict__ xb,
                                                const unsigned short* __restrict__ wb,
                                                unsigned short* __restrict__ Qp,
                                                unsigned short* __restrict__ Kp,
                                                unsigned short* __restrict__ Vt) {
  __shared__ unsigned short As[128 * 32];
  __shared__ unsigned short Bs[128 * 32];
  f32x4 acc[4][4];
#pragma unroll
  for (int i = 0; i < 4; ++i)
#pragma unroll
    for (int j = 0; j < 4; ++j) acc[i][j] = f32x4{0.f, 0.f, 0.f, 0.f};
  int id = (blockIdx.x & 7) * 96 + (blockIdx.x >> 3);  // bijective (768 % 8 == 0)
  int tm = id / 24, tn = id % 24;
  gemm128_bt(xb, wb, As, Bs, tm, tn, acc);

  int tid = threadIdx.x;
  int w = tid >> 6, l = tid & 63;
  int wr = w >> 1, wc = w & 1;
  int g = l >> 4, c = l & 15;
  const float QSCALE = 0.125f * 1.44269504088896f;  // hd^-0.5 * log2(e)
#pragma unroll
  for (int mi = 0; mi < 4; ++mi)
#pragma unroll
    for (int ni = 0; ni < 4; ++ni)
#pragma unroll
      for (int r = 0; r < 4; ++r) {
        int row = tm * 128 + wr * 64 + mi * 16 + g * 4 + r;   // 0..4095
        int col = tn * 128 + wc * 64 + ni * 16 + c;           // 0..3071
        int b = row >> 11, seq = row & 2047;
        int t = col >> 10;
        int h = (col >> 6) & 15, d = col & 63;
        size_t bh = (size_t)b * 16 + h;
        float v = acc[mi][ni][r];
        if (t == 0)      Qp[(bh * 2048 + seq) * 64 + d] = f2bf(v * QSCALE);
        else if (t == 1) Kp[(bh * 2048 + seq) * 64 + d] = f2bf(v);
        else             Vt[(bh * 64 + d) * 2048 + seq] = f2bf(v);           // transposed V
      }
}

// ---------------- block-causal flash attention: paired q-blocks, shared K/V frags ----------------
// Round-9 proven inner loop (swapped QK^T, in-register P, V in LDS). One block = q-blocks
// {2p, 2p+1}: per k-tile, kf/vf LDS reads are shared by BOTH q-block computations -> LDS
// bytes per MFMA halve. Control flow block-uniform (lower q skips only the last tile).
// Heavy pairs (p=15) dispatch first. 512 blocks, 4 waves, 32KB LDS, ~3 blocks/CU.
__global__ __launch_bounds__(256, 3) void attn_fa(const unsigned short* __restrict__ Qp,
                                                  const unsigned short* __restrict__ Kp,
                                                  const unsigned short* __restrict__ Vt,
                                                  unsigned short* __restrict__ attn) {
  __shared__ unsigned short Ks[2][4096];   // [buf][64 rows x 64 elems], swizzled
  __shared__ unsigned short Vs[2][4096];   // [buf][64 d-rows x 64 seq], swizzled
  int tid = threadIdx.x;
  int w = tid >> 6, l = tid & 63;
  int g = l >> 4, c = l & 15;

  int idx = blockIdx.x;                  // 512 blocks
  int pos = idx >> 3;                    // 0..63
  int p = 15 - (pos >> 2);               // heavy pairs first
  int bh = (idx & 7) + 8 * (pos & 3);    // 4 bh per XCD slot (K/V L2 locality)
  int qlo = 2 * p, qhi = 2 * p + 1;

  const unsigned short* Qbh = Qp + (size_t)bh * 2048 * 64;
  const unsigned short* Kbh = Kp + (size_t)bh * 2048 * 64;
  const unsigned short* Vbh = Vt + (size_t)bh * 64 * 2048;

  int rowA, colA, rowB, colB;
  { int L = tid * 16;         int P = L ^ (((L >> 7) & 7) << 4); rowA = P >> 7; colA = (P & 127) >> 1; }
  { int L = (tid + 256) * 16; int P = L ^ (((L >> 7) & 7) << 4); rowB = P >> 7; colB = (P & 127) >> 1; }
  const unsigned short* gKA = Kbh + rowA * 64 + colA;            // + kb*4096
  const unsigned short* gKB = Kbh + rowB * 64 + colB;
  const unsigned short* gVA = Vbh + (size_t)rowA * 2048 + colA;  // + kb*64
  const unsigned short* gVB = Vbh + (size_t)rowB * 2048 + colB;

#define STAGE(buf, kb)                                              \
  do {                                                              \
    gload_lds16(gKA + (kb) * 4096, &Ks[(buf)][w * 512]);            \
    gload_lds16(gKB + (kb) * 4096, &Ks[(buf)][w * 512 + 2048]);     \
    gload_lds16(gVA + (kb) * 64,  &Vs[(buf)][w * 512]);             \
    gload_lds16(gVB + (kb) * 64,  &Vs[(buf)][w * 512 + 2048]);      \
  } while (0)

  // Q fragments for wave's 16 rows of BOTH q-blocks
  bf16x8 qfl[2], qfh[2];
  {
    size_t qr0 = (size_t)qlo * 64 + w * 16 + c;
    size_t qr1 = (size_t)qhi * 64 + w * 16 + c;
    qfl[0] = *(const bf16x8*)(Qbh + qr0 * 64 + 8 * g);
    qfl[1] = *(const bf16x8*)(Qbh + qr0 * 64 + 32 + 8 * g);
    qfh[0] = *(const bf16x8*)(Qbh + qr1 * 64 + 8 * g);
    qfh[1] = *(const bf16x8*)(Qbh + qr1 * 64 + 32 + 8 * g);
  }

  float lpl[4] = {0.f, 0.f, 0.f, 0.f}, lph[4] = {0.f, 0.f, 0.f, 0.f};
  f32x4 ol[4], oh[4];
#pragma unroll
  for (int df = 0; df < 4; ++df) { ol[df] = f32x4{0.f, 0.f, 0.f, 0.f}; oh[df] = f32x4{0.f, 0.f, 0.f, 0.f}; }

  int xorv = c & 7;

  int cur = 0;
  STAGE(0, 0);
  __syncthreads();
  int last = qhi;  // kb = 0..qhi; lower q-block skips kb == qhi
  for (int kb = 0; kb <= last; ++kb) {
    if (kb < last) STAGE(1 - cur, kb + 1);
    bool do_lo = (kb <= qlo);  // block-uniform

    const char* Kb = (const char*)&Ks[cur][0];
    const char* Vb = (const char*)&Vs[cur][0];
    // K fragments, shared by both q-blocks
    bf16x8 kf[8];
#pragma unroll
    for (int nf = 0; nf < 4; ++nf) {
      int r = nf * 16 + c;
#pragma unroll
      for (int ks = 0; ks < 2; ++ks)
        kf[nf * 2 + ks] = *(const bf16x8*)(Kb + r * 128 + (((ks * 4 + g) ^ xorv) * 16));
    }
    // swapped QK^T: s[nf][r] = S[q=c][k = nf*16 + 4g + r]
    f32x4 sl[4], sh[4];
#pragma unroll
    for (int nf = 0; nf < 4; ++nf) {
      sh[nf] = f32x4{0.f, 0.f, 0.f, 0.f};
      sh[nf] = __builtin_amdgcn_mfma_f32_16x16x32_bf16(kf[nf * 2 + 0], qfh[0], sh[nf], 0, 0, 0);
      sh[nf] = __builtin_amdgcn_mfma_f32_16x16x32_bf16(kf[nf * 2 + 1], qfh[1], sh[nf], 0, 0, 0);
    }
    if (do_lo) {
#pragma unroll
      for (int nf = 0; nf < 4; ++nf) {
        sl[nf] = f32x4{0.f, 0.f, 0.f, 0.f};
        sl[nf] = __builtin_amdgcn_mfma_f32_16x16x32_bf16(kf[nf * 2 + 0], qfl[0], sl[nf], 0, 0, 0);
        sl[nf] = __builtin_amdgcn_mfma_f32_16x16x32_bf16(kf[nf * 2 + 1], qfl[1], sl[nf], 0, 0, 0);
      }
    }
    // exp2 + pack to PV A-fragments
    u32x2 pal[4], pah[4];
#pragma unroll
    for (int nf = 0; nf < 4; ++nf) {
      float p0 = __builtin_amdgcn_exp2f(sh[nf][0]);
      float p1 = __builtin_amdgcn_exp2f(sh[nf][1]);
      float p2 = __builtin_amdgcn_exp2f(sh[nf][2]);
      float p3 = __builtin_amdgcn_exp2f(sh[nf][3]);
      lph[nf] += (p0 + p1) + (p2 + p3);
      unsigned int w0, w1;
      asm("v_cvt_pk_bf16_f32 %0, %1, %2" : "=v"(w0) : "v"(p0), "v"(p1));
      asm("v_cvt_pk_bf16_f32 %0, %1, %2" : "=v"(w1) : "v"(p2), "v"(p3));
      pah[nf][0] = w0; pah[nf][1] = w1;
    }
    if (do_lo) {
#pragma unroll
      for (int nf = 0; nf < 4; ++nf) {
        float p0 = __builtin_amdgcn_exp2f(sl[nf][0]);
        float p1 = __builtin_amdgcn_exp2f(sl[nf][1]);
        float p2 = __builtin_amdgcn_exp2f(sl[nf][2]);
        float p3 = __builtin_amdgcn_exp2f(sl[nf][3]);
        lpl[nf] += (p0 + p1) + (p2 + p3);
        unsigned int w0, w1;
        asm("v_cvt_pk_bf16_f32 %0, %1, %2" : "=v"(w0) : "v"(p0), "v"(p1));
        asm("v_cvt_pk_bf16_f32 %0, %1, %2" : "=v"(w1) : "v"(p2), "v"(p3));
        pal[nf][0] = w0; pal[nf][1] = w1;
      }
    }
    // PV: V fragment read ONCE, used by both q-blocks
#pragma unroll
    for (int df = 0; df < 4; ++df) {
      int vrow = df * 16 + c;
#pragma unroll
      for (int ks = 0; ks < 4; ++ks) {
        u32x2 vbf = *(const u32x2*)(Vb + vrow * 128 + (((2 * ks + (g >> 1)) ^ xorv) * 16) + 8 * (g & 1));
        asm("v_mfma_f32_16x16x16_bf16 %0, %1, %2, %0" : "+v"(oh[df]) : "v"(pah[ks]), "v"(vbf));
        if (do_lo)
          asm("v_mfma_f32_16x16x16_bf16 %0, %1, %2, %0" : "+v"(ol[df]) : "v"(pal[ks]), "v"(vbf));
      }
    }
    __syncthreads();
    cur ^= 1;
  }
#undef STAGE

  // denominators (per-lane partials all belong to q-row c)
  float sl2 = (lpl[0] + lpl[1]) + (lpl[2] + lpl[3]);
  float sh2 = (lph[0] + lph[1]) + (lph[2] + lph[3]);
  sl2 += __shfl_xor(sl2, 16); sl2 += __shfl_xor(sl2, 32);
  sh2 += __shfl_xor(sh2, 16); sh2 += __shfl_xor(sh2, 32);
  float invl[4], invh[4];
#pragma unroll
  for (int r = 0; r < 4; ++r) {
    invl[r] = __builtin_amdgcn_rcpf(__shfl(sl2, g * 4 + r));
    invh[r] = __builtin_amdgcn_rcpf(__shfl(sh2, g * 4 + r));
  }

  int b = bh >> 4, h = bh & 15;
#pragma unroll
  for (int df = 0; df < 4; ++df)
#pragma unroll
    for (int r = 0; r < 4; ++r) {
      int colc = h * 64 + df * 16 + c;
      int rl = qlo * 64 + w * 16 + g * 4 + r;
      int rh = qhi * 64 + w * 16 + g * 4 + r;
      attn[((size_t)b * 2048 + rl) * 1024 + colc] = f2bf(ol[df][r] * invl[r]);
      attn[((size_t)b * 2048 + rh) * 1024 + colc] = f2bf(oh[df][r] * invh[r]);
    }
}

// ---------------- output projection + bias (fp32 out) ----------------
__global__ __launch_bounds__(256) void proj_gemm(const unsigned short* __restrict__ attn,
                                                 const unsigned short* __restrict__ wpb,
                                                 const float* __restrict__ bias,
                                                 float* __restrict__ out) {
  __shared__ unsigned short As[128 * 32];
  __shared__ unsigned short Bs[128 * 32];
  f32x4 acc[4][4];
#pragma unroll
  for (int i = 0; i < 4; ++i)
#pragma unroll
    for (int j = 0; j < 4; ++j) acc[i][j] = f32x4{0.f, 0.f, 0.f, 0.f};
  int id = (blockIdx.x & 7) * 32 + (blockIdx.x >> 3);  // bijective (256 % 8 == 0)
  int tm = id / 8, tn = id % 8;
  gemm128_bt(attn, wpb, As, Bs, tm, tn, acc);

  int tid = threadIdx.x;
  int w = tid >> 6, l = tid & 63;
  int wr = w >> 1, wc = w & 1;
  int g = l >> 4, c = l & 15;
#pragma unroll
  for (int mi = 0; mi < 4; ++mi)
#pragma unroll
    for (int ni = 0; ni < 4; ++ni)
#pragma unroll
      for (int r = 0; r < 4; ++r) {
        int row = tm * 128 + wr * 64 + mi * 16 + g * 4 + r;
        int col = tn * 128 + wc * 64 + ni * 16 + c;
        out[(size_t)row * 1024 + col] = acc[mi][ni][r] + bias[col];
      }
}

extern "C" void kernel_launch(void* const* d_in, const int* in_sizes, int n_in,
                              void* d_out, int out_size, void* d_ws, size_t ws_size,
                              hipStream_t stream) {
  (void)in_sizes; (void)n_in; (void)out_size; (void)ws_size;
  const float* x      = (const float*)d_in[0];  // [2,2048,1024]
  const float* w_qkv  = (const float*)d_in[1];  // [3072,1024]
  const float* w_proj = (const float*)d_in[2];  // [1024,1024]
  const float* b_proj = (const float*)d_in[3];  // [1024]
  float* out = (float*)d_out;

  unsigned short* xb    = (unsigned short*)d_ws;          // 4096*1024
  unsigned short* wqkvb = xb + 4096 * 1024;               // 3072*1024
  unsigned short* wpb   = wqkvb + 3072 * 1024;            // 1024*1024
  unsigned short* Qp    = wpb + 1024 * 1024;              // 32*2048*64
  unsigned short* Kp    = Qp + 32 * 2048 * 64;            // 32*2048*64
  unsigned short* Vt    = Kp + 32 * 2048 * 64;            // 32*64*2048
  unsigned short* attn  = Vt + 32 * 64 * 2048;            // 4096*1024

  cvt_all<<<1024, 256, 0, stream>>>(x, w_qkv, w_proj, xb);
  qkv_gemm<<<768, 256, 0, stream>>>(xb, wqkvb, Qp, Kp, Vt);
  attn_fa<<<512, 256, 0, stream>>>(Qp, Kp, Vt, attn);
  proj_gemm<<<256, 256, 0, stream>>>(attn, wpb, b_proj, out);
}

// Round 12
// 120.420 us; speedup vs baseline: 1.8400x; 1.0169x over previous
//
#include <hip/hip_runtime.h>

typedef __attribute__((ext_vector_type(8))) short bf16x8;
typedef __attribute__((ext_vector_type(4))) float f32x4;
typedef __attribute__((ext_vector_type(2))) unsigned int u32x2;
typedef __attribute__((ext_vector_type(8))) unsigned short ushort8v;

__device__ __forceinline__ unsigned short f2bf(float f) {
  unsigned int u = __float_as_uint(f);
  u += 0x7fffu + ((u >> 16) & 1u);  // round-to-nearest-even
  return (unsigned short)(u >> 16);
}

__device__ __forceinline__ void gload_lds16(const unsigned short* g, unsigned short* l) {
  __builtin_amdgcn_global_load_lds(
      (const __attribute__((address_space(1))) unsigned int*)g,
      (__attribute__((address_space(3))) unsigned int*)l,
      16, 0, 0);
}

// ---------------- fused fp32 -> bf16 convert: 8 elems/thread/iter, 16B stores ----------------
__global__ void cvt_all(const float* __restrict__ x, const float* __restrict__ wq,
                        const float* __restrict__ wp, unsigned short* __restrict__ dst) {
  const int n1 = 4096 * 1024 / 8, n2 = 3072 * 1024 / 8, n3 = 1024 * 1024 / 8;
  int stride = gridDim.x * blockDim.x;
  for (int i = blockIdx.x * blockDim.x + threadIdx.x; i < n1 + n2 + n3; i += stride) {
    const float* s; int j;
    if (i < n1)           { s = x;  j = i; }
    else if (i < n1 + n2) { s = wq; j = i - n1; }
    else                  { s = wp; j = i - n1 - n2; }
    float4 a = ((const float4*)s)[j * 2];
    float4 b = ((const float4*)s)[j * 2 + 1];
    ushort8v o;
    o[0] = f2bf(a.x); o[1] = f2bf(a.y); o[2] = f2bf(a.z); o[3] = f2bf(a.w);
    o[4] = f2bf(b.x); o[5] = f2bf(b.y); o[6] = f2bf(b.z); o[7] = f2bf(b.w);
    ((ushort8v*)dst)[i] = o;
  }
}

// ---------------- 128x128 gemm_bt: round-3 tile + SINGLE-BARRIER double-buffer ----------------
// Same pattern as the proven attn staging loop: stage tile t+1 into buf^1 while computing
// buf, then ONE __syncthreads() (drains stage vmcnt + protects buffer reuse). Stage latency
// hides under 16 MFMA instead of sitting on the critical path. Chunk-XOR swizzle kept
// (conflict-free ds_read_b128). LDS 2 x 8KB per operand = 32KB/block.
__device__ __forceinline__ void gemm128_bt(const unsigned short* __restrict__ A,
                                           const unsigned short* __restrict__ Bt,
                                           unsigned short* As, unsigned short* Bs,
                                           int tm, int tn, f32x4 acc[4][4]) {
  const int K = 1024;
  int tid = threadIdx.x;
  int w = tid >> 6, l = tid & 63;
  int wr = w >> 1, wc = w & 1;
  int g = l >> 4, c = l & 15;

  int srow = w * 32 + (l >> 2);
  int skoff = (((l & 3) ^ ((srow >> 1) & 3)) * 8);  // pre-swizzled source k-offset
  const unsigned short* gA = A + (size_t)(tm * 128 + srow) * K + skoff;
  const unsigned short* gB = Bt + (size_t)(tn * 128 + srow) * K + skoff;
  unsigned short* lA = As + (w * 32) * 32;  // wave-uniform LDS base (+ buf*4096)
  unsigned short* lB = Bs + (w * 32) * 32;

  int rx = (c >> 1) & 3;  // f(row) for all fragment rows (row = base16 + c)
  int arow = wr * 64 + c;
  int brow = wc * 64 + c;

#define STG(buf, t)                                                  \
  do {                                                               \
    const unsigned short* ga_ = gA + (t) * 32;                       \
    const unsigned short* gb_ = gB + (t) * 32;                       \
    gload_lds16(ga_, lA + (buf) * 4096);                             \
    gload_lds16(ga_ + 16 * K, lA + (buf) * 4096 + 16 * 32);          \
    gload_lds16(gb_, lB + (buf) * 4096);                             \
    gload_lds16(gb_ + 16 * K, lB + (buf) * 4096 + 16 * 32);          \
  } while (0)

  int cur = 0;
  STG(0, 0);
  __syncthreads();
  for (int t = 0; t < 32; ++t) {
    if (t + 1 < 32) STG(1 - cur, t + 1);  // prefetch next K-step into the other buffer
    const char* Ab = (const char*)(As + cur * 4096);
    const char* Bb = (const char*)(Bs + cur * 4096);
    bf16x8 af[4], bfr[4];
#pragma unroll
    for (int mi = 0; mi < 4; ++mi)
      af[mi] = *(const bf16x8*)(Ab + (arow + mi * 16) * 64 + ((g ^ rx) << 4));
#pragma unroll
    for (int ni = 0; ni < 4; ++ni)
      bfr[ni] = *(const bf16x8*)(Bb + (brow + ni * 16) * 64 + ((g ^ rx) << 4));
#pragma unroll
    for (int mi = 0; mi < 4; ++mi)
#pragma unroll
      for (int ni = 0; ni < 4; ++ni)
        acc[mi][ni] = __builtin_amdgcn_mfma_f32_16x16x32_bf16(af[mi], bfr[ni], acc[mi][ni], 0, 0, 0);
    __syncthreads();  // stage landed (vmcnt drained) + reads of cur done before overwrite
    cur ^= 1;
  }
#undef STG
}

// ---------------- QKV projection: scatter into Q (scaled), K, V^T ----------------
__global__ __launch_bounds__(256) void qkv_gemm(const unsigned short* __restrict__ xb,
                                                const unsigned short* __restrict__ wb,
                                                unsigned short* __restrict__ Qp,
                                                unsigned short* __restrict__ Kp,
                                                unsigned short* __restrict__ Vt) {
  __shared__ unsigned short As[2 * 128 * 32];
  __shared__ unsigned short Bs[2 * 128 * 32];
  f32x4 acc[4][4];
#pragma unroll
  for (int i = 0; i < 4; ++i)
#pragma unroll
    for (int j = 0; j < 4; ++j) acc[i][j] = f32x4{0.f, 0.f, 0.f, 0.f};
  int id = (blockIdx.x & 7) * 96 + (blockIdx.x >> 3);  // bijective (768 % 8 == 0)
  int tm = id / 24, tn = id % 24;
  gemm128_bt(xb, wb, As, Bs, tm, tn, acc);

  int tid = threadIdx.x;
  int w = tid >> 6, l = tid & 63;
  int wr = w >> 1, wc = w & 1;
  int g = l >> 4, c = l & 15;
  const float QSCALE = 0.125f * 1.44269504088896f;  // hd^-0.5 * log2(e)
#pragma unroll
  for (int mi = 0; mi < 4; ++mi)
#pragma unroll
    for (int ni = 0; ni < 4; ++ni)
#pragma unroll
      for (int r = 0; r < 4; ++r) {
        int row = tm * 128 + wr * 64 + mi * 16 + g * 4 + r;   // 0..4095
        int col = tn * 128 + wc * 64 + ni * 16 + c;           // 0..3071
        int b = row >> 11, seq = row & 2047;
        int t = col >> 10;
        int h = (col >> 6) & 15, d = col & 63;
        size_t bh = (size_t)b * 16 + h;
        float v = acc[mi][ni][r];
        if (t == 0)      Qp[(bh * 2048 + seq) * 64 + d] = f2bf(v * QSCALE);
        else if (t == 1) Kp[(bh * 2048 + seq) * 64 + d] = f2bf(v);
        else             Vt[(bh * 64 + d) * 2048 + seq] = f2bf(v);           // transposed V
      }
}

// ---------------- block-causal flash attention (round-9 proven): swapped QK^T, in-reg P --------
// mfma(K,Q): P[q=c][k=nf*16+4g+r] lane-local -> cvt_pk -> x16-MFMA A-frags, no LDS round-trip.
// K and V double-buffered in LDS (XOR-swizzled via pre-swizzled global source).
__global__ __launch_bounds__(256, 3) void attn_fa(const unsigned short* __restrict__ Qp,
                                                  const unsigned short* __restrict__ Kp,
                                                  const unsigned short* __restrict__ Vt,
                                                  unsigned short* __restrict__ attn) {
  __shared__ unsigned short Ks[2][4096];   // [buf][64 rows x 64 elems], swizzled
  __shared__ unsigned short Vs[2][4096];   // [buf][64 d-rows x 64 seq], swizzled
  int tid = threadIdx.x;
  int w = tid >> 6, l = tid & 63;
  int g = l >> 4, c = l & 15;

  int idx = blockIdx.x;
  int pos = idx >> 3;                    // 0..127
  int qb = 31 - (pos >> 2);              // heavy blocks dispatch first
  int bh = (idx & 7) + 8 * (pos & 3);    // 4 bh per XCD slot (K/V L2 locality)

  const unsigned short* Qbh = Qp + (size_t)bh * 2048 * 64;
  const unsigned short* Kbh = Kp + (size_t)bh * 2048 * 64;
  const unsigned short* Vbh = Vt + (size_t)bh * 64 * 2048;

  int rowA, colA, rowB, colB;
  { int L = tid * 16;         int P = L ^ (((L >> 7) & 7) << 4); rowA = P >> 7; colA = (P & 127) >> 1; }
  { int L = (tid + 256) * 16; int P = L ^ (((L >> 7) & 7) << 4); rowB = P >> 7; colB = (P & 127) >> 1; }
  const unsigned short* gKA = Kbh + rowA * 64 + colA;            // + kb*4096
  const unsigned short* gKB = Kbh + rowB * 64 + colB;
  const unsigned short* gVA = Vbh + (size_t)rowA * 2048 + colA;  // + kb*64
  const unsigned short* gVB = Vbh + (size_t)rowB * 2048 + colB;

#define STAGE(buf, kb)                                              \
  do {                                                              \
    gload_lds16(gKA + (kb) * 4096, &Ks[(buf)][w * 512]);            \
    gload_lds16(gKB + (kb) * 4096, &Ks[(buf)][w * 512 + 2048]);     \
    gload_lds16(gVA + (kb) * 64,  &Vs[(buf)][w * 512]);             \
    gload_lds16(gVB + (kb) * 64,  &Vs[(buf)][w * 512 + 2048]);      \
  } while (0)

  bf16x8 qf[2];
  {
    size_t qrow = (size_t)qb * 64 + w * 16 + c;
    qf[0] = *(const bf16x8*)(Qbh + qrow * 64 + 8 * g);
    qf[1] = *(const bf16x8*)(Qbh + qrow * 64 + 32 + 8 * g);
  }

  float lp4[4] = {0.f, 0.f, 0.f, 0.f};  // per-lane partial denominators (all for q-row c)
  f32x4 o[4];
#pragma unroll
  for (int df = 0; df < 4; ++df) o[df] = f32x4{0.f, 0.f, 0.f, 0.f};

  int xorv = c & 7;

  int cur = 0;
  STAGE(0, 0);
  __syncthreads();
  for (int kb = 0; kb <= qb; ++kb) {
    if (kb < qb) STAGE(1 - cur, kb + 1);

    const char* Kb = (const char*)&Ks[cur][0];
    const char* Vb = (const char*)&Vs[cur][0];
    // K fragments (A-operand)
    bf16x8 kf[8];
#pragma unroll
    for (int nf = 0; nf < 4; ++nf) {
      int r = nf * 16 + c;
#pragma unroll
      for (int ks = 0; ks < 2; ++ks)
        kf[nf * 2 + ks] = *(const bf16x8*)(Kb + r * 128 + (((ks * 4 + g) ^ xorv) * 16));
    }
    // swapped QK^T: s4[nf][r] = S[q=c][k = nf*16 + 4g + r]
    f32x4 s4[4];
#pragma unroll
    for (int nf = 0; nf < 4; ++nf) {
      s4[nf] = f32x4{0.f, 0.f, 0.f, 0.f};
      s4[nf] = __builtin_amdgcn_mfma_f32_16x16x32_bf16(kf[nf * 2 + 0], qf[0], s4[nf], 0, 0, 0);
      s4[nf] = __builtin_amdgcn_mfma_f32_16x16x32_bf16(kf[nf * 2 + 1], qf[1], s4[nf], 0, 0, 0);
    }
    // exp2 + in-register pack to PV A-fragments
    u32x2 pa[4];
#pragma unroll
    for (int nf = 0; nf < 4; ++nf) {
      float p0 = __builtin_amdgcn_exp2f(s4[nf][0]);
      float p1 = __builtin_amdgcn_exp2f(s4[nf][1]);
      float p2 = __builtin_amdgcn_exp2f(s4[nf][2]);
      float p3 = __builtin_amdgcn_exp2f(s4[nf][3]);
      lp4[nf] += (p0 + p1) + (p2 + p3);
      unsigned int w0, w1;
      asm("v_cvt_pk_bf16_f32 %0, %1, %2" : "=v"(w0) : "v"(p0), "v"(p1));
      asm("v_cvt_pk_bf16_f32 %0, %1, %2" : "=v"(w1) : "v"(p2), "v"(p3));
      pa[nf][0] = w0; pa[nf][1] = w1;
    }
    // PV: O[q][d] += P[q][k] V[k][d] via 16x16x16 (B-frag: V[k=4g+j][d=c] from Vs b64 reads)
#pragma unroll
    for (int df = 0; df < 4; ++df) {
      int vrow = df * 16 + c;
#pragma unroll
      for (int ks = 0; ks < 4; ++ks) {
        u32x2 vbf = *(const u32x2*)(Vb + vrow * 128 + (((2 * ks + (g >> 1)) ^ xorv) * 16) + 8 * (g & 1));
        asm("v_mfma_f32_16x16x16_bf16 %0, %1, %2, %0"
            : "+v"(o[df]) : "v"(pa[ks]), "v"(vbf));
      }
    }
    __syncthreads();
    cur ^= 1;
  }
#undef STAGE

  // denominator: all partials in this lane belong to q-row c
  float lp = (lp4[0] + lp4[1]) + (lp4[2] + lp4[3]);
  lp += __shfl_xor(lp, 16);
  lp += __shfl_xor(lp, 32);
  float inv[4];
#pragma unroll
  for (int r = 0; r < 4; ++r) inv[r] = __builtin_amdgcn_rcpf(__shfl(lp, g * 4 + r));

  int b = bh >> 4, h = bh & 15;
#pragma unroll
  for (int df = 0; df < 4; ++df)
#pragma unroll
    for (int r = 0; r < 4; ++r) {
      int row = qb * 64 + w * 16 + g * 4 + r;
      int colc = h * 64 + df * 16 + c;
      attn[((size_t)b * 2048 + row) * 1024 + colc] = f2bf(o[df][r] * inv[r]);
    }
}

// ---------------- output projection + bias (fp32 out) ----------------
__global__ __launch_bounds__(256) void proj_gemm(const unsigned short* __restrict__ attn,
                                                 const unsigned short* __restrict__ wpb,
                                                 const float* __restrict__ bias,
                                                 float* __restrict__ out) {
  __shared__ unsigned short As[2 * 128 * 32];
  __shared__ unsigned short Bs[2 * 128 * 32];
  f32x4 acc[4][4];
#pragma unroll
  for (int i = 0; i < 4; ++i)
#pragma unroll
    for (int j = 0; j < 4; ++j) acc[i][j] = f32x4{0.f, 0.f, 0.f, 0.f};
  int id = (blockIdx.x & 7) * 32 + (blockIdx.x >> 3);  // bijective (256 % 8 == 0)
  int tm = id / 8, tn = id % 8;
  gemm128_bt(attn, wpb, As, Bs, tm, tn, acc);

  int tid = threadIdx.x;
  int w = tid >> 6, l = tid & 63;
  int wr = w >> 1, wc = w & 1;
  int g = l >> 4, c = l & 15;
#pragma unroll
  for (int mi = 0; mi < 4; ++mi)
#pragma unroll
    for (int ni = 0; ni < 4; ++ni)
#pragma unroll
      for (int r = 0; r < 4; ++r) {
        int row = tm * 128 + wr * 64 + mi * 16 + g * 4 + r;
        int col = tn * 128 + wc * 64 + ni * 16 + c;
        out[(size_t)row * 1024 + col] = acc[mi][ni][r] + bias[col];
      }
}

extern "C" void kernel_launch(void* const* d_in, const int* in_sizes, int n_in,
                              void* d_out, int out_size, void* d_ws, size_t ws_size,
                              hipStream_t stream) {
  (void)in_sizes; (void)n_in; (void)out_size; (void)ws_size;
  const float* x      = (const float*)d_in[0];  // [2,2048,1024]
  const float* w_qkv  = (const float*)d_in[1];  // [3072,1024]
  const float* w_proj = (const float*)d_in[2];  // [1024,1024]
  const float* b_proj = (const float*)d_in[3];  // [1024]
  float* out = (float*)d_out;

  unsigned short* xb    = (unsigned short*)d_ws;          // 4096*1024
  unsigned short* wqkvb = xb + 4096 * 1024;               // 3072*1024
  unsigned short* wpb   = wqkvb + 3072 * 1024;            // 1024*1024
  unsigned short* Qp    = wpb + 1024 * 1024;              // 32*2048*64
  unsigned short* Kp    = Qp + 32 * 2048 * 64;            // 32*2048*64
  unsigned short* Vt    = Kp + 32 * 2048 * 64;            // 32*64*2048
  unsigned short* attn  = Vt + 32 * 64 * 2048;            // 4096*1024

  cvt_all<<<1024, 256, 0, stream>>>(x, w_qkv, w_proj, xb);
  qkv_gemm<<<768, 256, 0, stream>>>(xb, wqkvb, Qp, Kp, Vt);
  attn_fa<<<1024, 256, 0, stream>>>(Qp, Kp, Vt, attn);
  proj_gemm<<<256, 256, 0, stream>>>(attn, wpb, b_proj, out);
}

// Round 13
// 109.708 us; speedup vs baseline: 2.0196x; 1.0976x over previous
//
#include <hip/hip_runtime.h>

typedef __attribute__((ext_vector_type(8))) short bf16x8;
typedef __attribute__((ext_vector_type(4))) float f32x4;
typedef __attribute__((ext_vector_type(2))) unsigned int u32x2;
typedef __attribute__((ext_vector_type(8))) unsigned short ushort8v;

__device__ __forceinline__ unsigned short f2bf(float f) {
  unsigned int u = __float_as_uint(f);
  u += 0x7fffu + ((u >> 16) & 1u);  // round-to-nearest-even
  return (unsigned short)(u >> 16);
}

__device__ __forceinline__ void gload_lds16(const unsigned short* g, unsigned short* l) {
  __builtin_amdgcn_global_load_lds(
      (const __attribute__((address_space(1))) unsigned int*)g,
      (__attribute__((address_space(3))) unsigned int*)l,
      16, 0, 0);
}

// ---------------- fused fp32 -> bf16 convert: 8 elems/thread/iter, 16B stores ----------------
__global__ void cvt_all(const float* __restrict__ x, const float* __restrict__ wq,
                        const float* __restrict__ wp, unsigned short* __restrict__ dst) {
  const int n1 = 4096 * 1024 / 8, n2 = 3072 * 1024 / 8, n3 = 1024 * 1024 / 8;
  int stride = gridDim.x * blockDim.x;
  for (int i = blockIdx.x * blockDim.x + threadIdx.x; i < n1 + n2 + n3; i += stride) {
    const float* s; int j;
    if (i < n1)           { s = x;  j = i; }
    else if (i < n1 + n2) { s = wq; j = i - n1; }
    else                  { s = wp; j = i - n1 - n2; }
    float4 a = ((const float4*)s)[j * 2];
    float4 b = ((const float4*)s)[j * 2 + 1];
    ushort8v o;
    o[0] = f2bf(a.x); o[1] = f2bf(a.y); o[2] = f2bf(a.z); o[3] = f2bf(a.w);
    o[4] = f2bf(b.x); o[5] = f2bf(b.y); o[6] = f2bf(b.z); o[7] = f2bf(b.w);
    ((ushort8v*)dst)[i] = o;
  }
}

// ---------------- 128x128 gemm_bt (PROVEN round-3/8 2-barrier structure, chunk-XOR) ----------
// LDS [128][32] bf16 per operand (8KB). Stored chunk cc of row r holds global k-chunk
// cc ^ ((r>>1)&3): pre-swizzled global source (linear LDS dest, rule #21), same XOR on
// ds_read -> conflict-free ds_read_b128. Do NOT restructure this loop: 6 attempts
// (4-slot ring, 256^2 8-phase, BK=64, single-barrier dbuf) all regressed vs this.
__device__ __forceinline__ void gemm128_bt(const unsigned short* __restrict__ A,
                                           const unsigned short* __restrict__ Bt,
                                           unsigned short* As, unsigned short* Bs,
                                           int tm, int tn, f32x4 acc[4][4]) {
  const int K = 1024;
  int tid = threadIdx.x;
  int w = tid >> 6, l = tid & 63;
  int wr = w >> 1, wc = w & 1;
  int g = l >> 4, c = l & 15;

  int srow = w * 32 + (l >> 2);
  int skoff = (((l & 3) ^ ((srow >> 1) & 3)) * 8);  // pre-swizzled source k-offset
  const unsigned short* gA = A + (size_t)(tm * 128 + srow) * K + skoff;
  const unsigned short* gB = Bt + (size_t)(tn * 128 + srow) * K + skoff;
  unsigned short* lA = As + (w * 32) * 32;  // wave-uniform LDS base (linear dest)
  unsigned short* lB = Bs + (w * 32) * 32;

  int rx = (c >> 1) & 3;  // f(row) for all fragment rows (row = base16 + c)
  int arow = wr * 64 + c;
  int brow = wc * 64 + c;

  for (int k0 = 0; k0 < K; k0 += 32) {
    gload_lds16(gA, lA);
    gload_lds16(gA + 16 * K, lA + 16 * 32);  // row+16: same (r>>1)&3 -> same skoff
    gload_lds16(gB, lB);
    gload_lds16(gB + 16 * K, lB + 16 * 32);
    gA += 32; gB += 32;
    __syncthreads();
    bf16x8 af[4], bfr[4];
#pragma unroll
    for (int mi = 0; mi < 4; ++mi)
      af[mi] = *(const bf16x8*)((const char*)As + (arow + mi * 16) * 64 + ((g ^ rx) << 4));
#pragma unroll
    for (int ni = 0; ni < 4; ++ni)
      bfr[ni] = *(const bf16x8*)((const char*)Bs + (brow + ni * 16) * 64 + ((g ^ rx) << 4));
#pragma unroll
    for (int mi = 0; mi < 4; ++mi)
#pragma unroll
      for (int ni = 0; ni < 4; ++ni)
        acc[mi][ni] = __builtin_amdgcn_mfma_f32_16x16x32_bf16(af[mi], bfr[ni], acc[mi][ni], 0, 0, 0);
    __syncthreads();
  }
}

// ---------------- QKV projection: scatter into Q (scaled), K, V^T ----------------
__global__ __launch_bounds__(256) void qkv_gemm(const unsigned short* __restrict__ xb,
                                                const unsigned short* __restrict__ wb,
                                                unsigned short* __restrict__ Qp,
                                                unsigned short* __restrict__ Kp,
                                                unsigned short* __restrict__ Vt) {
  __shared__ unsigned short As[128 * 32];
  __shared__ unsigned short Bs[128 * 32];
  f32x4 acc[4][4];
#pragma unroll
  for (int i = 0; i < 4; ++i)
#pragma unroll
    for (int j = 0; j < 4; ++j) acc[i][j] = f32x4{0.f, 0.f, 0.f, 0.f};
  int id = (blockIdx.x & 7) * 96 + (blockIdx.x >> 3);  // bijective (768 % 8 == 0)
  int tm = id / 24, tn = id % 24;
  gemm128_bt(xb, wb, As, Bs, tm, tn, acc);

  int tid = threadIdx.x;
  int w = tid >> 6, l = tid & 63;
  int wr = w >> 1, wc = w & 1;
  int g = l >> 4, c = l & 15;
  const float QSCALE = 0.125f * 1.44269504088896f;  // hd^-0.5 * log2(e)
#pragma unroll
  for (int mi = 0; mi < 4; ++mi)
#pragma unroll
    for (int ni = 0; ni < 4; ++ni)
#pragma unroll
      for (int r = 0; r < 4; ++r) {
        int row = tm * 128 + wr * 64 + mi * 16 + g * 4 + r;   // 0..4095
        int col = tn * 128 + wc * 64 + ni * 16 + c;           // 0..3071
        int b = row >> 11, seq = row & 2047;
        int t = col >> 10;
        int h = (col >> 6) & 15, d = col & 63;
        size_t bh = (size_t)b * 16 + h;
        float v = acc[mi][ni][r];
        if (t == 0)      Qp[(bh * 2048 + seq) * 64 + d] = f2bf(v * QSCALE);
        else if (t == 1) Kp[(bh * 2048 + seq) * 64 + d] = f2bf(v);
        else             Vt[(bh * 64 + d) * 2048 + seq] = f2bf(v);           // transposed V
      }
}

// ---------------- block-causal flash attention (PROVEN round-8): swapped QK^T, in-reg P --------
// mfma(K,Q): P[q=c][k=nf*16+4g+r] lane-local -> cvt_pk -> x16-MFMA A-frags, no LDS round-trip.
// K and V double-buffered in LDS (XOR-swizzled via pre-swizzled global source).
__global__ __launch_bounds__(256, 3) void attn_fa(const unsigned short* __restrict__ Qp,
                                                  const unsigned short* __restrict__ Kp,
                                                  const unsigned short* __restrict__ Vt,
                                                  unsigned short* __restrict__ attn) {
  __shared__ unsigned short Ks[2][4096];   // [buf][64 rows x 64 elems], swizzled
  __shared__ unsigned short Vs[2][4096];   // [buf][64 d-rows x 64 seq], swizzled
  int tid = threadIdx.x;
  int w = tid >> 6, l = tid & 63;
  int g = l >> 4, c = l & 15;

  int idx = blockIdx.x;
  int pos = idx >> 3;                    // 0..127
  int qb = 31 - (pos >> 2);              // heavy blocks dispatch first
  int bh = (idx & 7) + 8 * (pos & 3);    // 4 bh per XCD slot (K/V L2 locality)

  const unsigned short* Qbh = Qp + (size_t)bh * 2048 * 64;
  const unsigned short* Kbh = Kp + (size_t)bh * 2048 * 64;
  const unsigned short* Vbh = Vt + (size_t)bh * 64 * 2048;

  int rowA, colA, rowB, colB;
  { int L = tid * 16;         int P = L ^ (((L >> 7) & 7) << 4); rowA = P >> 7; colA = (P & 127) >> 1; }
  { int L = (tid + 256) * 16; int P = L ^ (((L >> 7) & 7) << 4); rowB = P >> 7; colB = (P & 127) >> 1; }
  const unsigned short* gKA = Kbh + rowA * 64 + colA;            // + kb*4096
  const unsigned short* gKB = Kbh + rowB * 64 + colB;
  const unsigned short* gVA = Vbh + (size_t)rowA * 2048 + colA;  // + kb*64
  const unsigned short* gVB = Vbh + (size_t)rowB * 2048 + colB;

#define STAGE(buf, kb)                                              \
  do {                                                              \
    gload_lds16(gKA + (kb) * 4096, &Ks[(buf)][w * 512]);            \
    gload_lds16(gKB + (kb) * 4096, &Ks[(buf)][w * 512 + 2048]);     \
    gload_lds16(gVA + (kb) * 64,  &Vs[(buf)][w * 512]);             \
    gload_lds16(gVB + (kb) * 64,  &Vs[(buf)][w * 512 + 2048]);      \
  } while (0)

  bf16x8 qf[2];
  {
    size_t qrow = (size_t)qb * 64 + w * 16 + c;
    qf[0] = *(const bf16x8*)(Qbh + qrow * 64 + 8 * g);
    qf[1] = *(const bf16x8*)(Qbh + qrow * 64 + 32 + 8 * g);
  }

  float lp4[4] = {0.f, 0.f, 0.f, 0.f};  // per-lane partial denominators (all for q-row c)
  f32x4 o[4];
#pragma unroll
  for (int df = 0; df < 4; ++df) o[df] = f32x4{0.f, 0.f, 0.f, 0.f};

  int xorv = c & 7;

  int cur = 0;
  STAGE(0, 0);
  __syncthreads();
  for (int kb = 0; kb <= qb; ++kb) {
    if (kb < qb) STAGE(1 - cur, kb + 1);

    const char* Kb = (const char*)&Ks[cur][0];
    const char* Vb = (const char*)&Vs[cur][0];
    // K fragments (A-operand)
    bf16x8 kf[8];
#pragma unroll
    for (int nf = 0; nf < 4; ++nf) {
      int r = nf * 16 + c;
#pragma unroll
      for (int ks = 0; ks < 2; ++ks)
        kf[nf * 2 + ks] = *(const bf16x8*)(Kb + r * 128 + (((ks * 4 + g) ^ xorv) * 16));
    }
    // swapped QK^T: s4[nf][r] = S[q=c][k = nf*16 + 4g + r]
    f32x4 s4[4];
#pragma unroll
    for (int nf = 0; nf < 4; ++nf) {
      s4[nf] = f32x4{0.f, 0.f, 0.f, 0.f};
      s4[nf] = __builtin_amdgcn_mfma_f32_16x16x32_bf16(kf[nf * 2 + 0], qf[0], s4[nf], 0, 0, 0);
      s4[nf] = __builtin_amdgcn_mfma_f32_16x16x32_bf16(kf[nf * 2 + 1], qf[1], s4[nf], 0, 0, 0);
    }
    // exp2 + in-register pack to PV A-fragments
    u32x2 pa[4];
#pragma unroll
    for (int nf = 0; nf < 4; ++nf) {
      float p0 = __builtin_amdgcn_exp2f(s4[nf][0]);
      float p1 = __builtin_amdgcn_exp2f(s4[nf][1]);
      float p2 = __builtin_amdgcn_exp2f(s4[nf][2]);
      float p3 = __builtin_amdgcn_exp2f(s4[nf][3]);
      lp4[nf] += (p0 + p1) + (p2 + p3);
      unsigned int w0, w1;
      asm("v_cvt_pk_bf16_f32 %0, %1, %2" : "=v"(w0) : "v"(p0), "v"(p1));
      asm("v_cvt_pk_bf16_f32 %0, %1, %2" : "=v"(w1) : "v"(p2), "v"(p3));
      pa[nf][0] = w0; pa[nf][1] = w1;
    }
    // PV: O[q][d] += P[q][k] V[k][d] via 16x16x16 (B-frag: V[k=4g+j][d=c] from Vs b64 reads)
#pragma unroll
    for (int df = 0; df < 4; ++df) {
      int vrow = df * 16 + c;
#pragma unroll
      for (int ks = 0; ks < 4; ++ks) {
        u32x2 vbf = *(const u32x2*)(Vb + vrow * 128 + (((2 * ks + (g >> 1)) ^ xorv) * 16) + 8 * (g & 1));
        asm("v_mfma_f32_16x16x16_bf16 %0, %1, %2, %0"
            : "+v"(o[df]) : "v"(pa[ks]), "v"(vbf));
      }
    }
    __syncthreads();
    cur ^= 1;
  }
#undef STAGE

  // denominator: all partials in this lane belong to q-row c
  float lp = (lp4[0] + lp4[1]) + (lp4[2] + lp4[3]);
  lp += __shfl_xor(lp, 16);
  lp += __shfl_xor(lp, 32);
  float inv[4];
#pragma unroll
  for (int r = 0; r < 4; ++r) inv[r] = __builtin_amdgcn_rcpf(__shfl(lp, g * 4 + r));

  int b = bh >> 4, h = bh & 15;
#pragma unroll
  for (int df = 0; df < 4; ++df)
#pragma unroll
    for (int r = 0; r < 4; ++r) {
      int row = qb * 64 + w * 16 + g * 4 + r;
      int colc = h * 64 + df * 16 + c;
      attn[((size_t)b * 2048 + row) * 1024 + colc] = f2bf(o[df][r] * inv[r]);
    }
}

// ---------------- output projection + bias (fp32 out) ----------------
__global__ __launch_bounds__(256) void proj_gemm(const unsigned short* __restrict__ attn,
                                                 const unsigned short* __restrict__ wpb,
                                                 const float* __restrict__ bias,
                                                 float* __restrict__ out) {
  __shared__ unsigned short As[128 * 32];
  __shared__ unsigned short Bs[128 * 32];
  f32x4 acc[4][4];
#pragma unroll
  for (int i = 0; i < 4; ++i)
#pragma unroll
    for (int j = 0; j < 4; ++j) acc[i][j] = f32x4{0.f, 0.f, 0.f, 0.f};
  int id = (blockIdx.x & 7) * 32 + (blockIdx.x >> 3);  // bijective (256 % 8 == 0)
  int tm = id / 8, tn = id % 8;
  gemm128_bt(attn, wpb, As, Bs, tm, tn, acc);

  int tid = threadIdx.x;
  int w = tid >> 6, l = tid & 63;
  int wr = w >> 1, wc = w & 1;
  int g = l >> 4, c = l & 15;
#pragma unroll
  for (int mi = 0; mi < 4; ++mi)
#pragma unroll
    for (int ni = 0; ni < 4; ++ni)
#pragma unroll
      for (int r = 0; r < 4; ++r) {
        int row = tm * 128 + wr * 64 + mi * 16 + g * 4 + r;
        int col = tn * 128 + wc * 64 + ni * 16 + c;
        out[(size_t)row * 1024 + col] = acc[mi][ni][r] + bias[col];
      }
}

extern "C" void kernel_launch(void* const* d_in, const int* in_sizes, int n_in,
                              void* d_out, int out_size, void* d_ws, size_t ws_size,
                              hipStream_t stream) {
  (void)in_sizes; (void)n_in; (void)out_size; (void)ws_size;
  const float* x      = (const float*)d_in[0];  // [2,2048,1024]
  const float* w_qkv  = (const float*)d_in[1];  // [3072,1024]
  const float* w_proj = (const float*)d_in[2];  // [1024,1024]
  const float* b_proj = (const float*)d_in[3];  // [1024]
  float* out = (float*)d_out;

  unsigned short* xb    = (unsigned short*)d_ws;          // 4096*1024
  unsigned short* wqkvb = xb + 4096 * 1024;               // 3072*1024
  unsigned short* wpb   = wqkvb + 3072 * 1024;            // 1024*1024
  unsigned short* Qp    = wpb + 1024 * 1024;              // 32*2048*64
  unsigned short* Kp    = Qp + 32 * 2048 * 64;            // 32*2048*64
  unsigned short* Vt    = Kp + 32 * 2048 * 64;            // 32*64*2048
  unsigned short* attn  = Vt + 32 * 64 * 2048;            // 4096*1024

  cvt_all<<<1024, 256, 0, stream>>>(x, w_qkv, w_proj, xb);
  qkv_gemm<<<768, 256, 0, stream>>>(xb, wqkvb, Qp, Kp, Vt);
  attn_fa<<<1024, 256, 0, stream>>>(Qp, Kp, Vt, attn);
  proj_gemm<<<256, 256, 0, stream>>>(attn, wpb, b_proj, out);
}

// Round 14
// 108.867 us; speedup vs baseline: 2.0353x; 1.0077x over previous
//
#include <hip/hip_runtime.h>

typedef __attribute__((ext_vector_type(8))) short bf16x8;
typedef __attribute__((ext_vector_type(4))) float f32x4;
typedef __attribute__((ext_vector_type(2))) unsigned int u32x2;
typedef __attribute__((ext_vector_type(8))) unsigned short ushort8v;

__device__ __forceinline__ unsigned short f2bf(float f) {
  unsigned int u = __float_as_uint(f);
  u += 0x7fffu + ((u >> 16) & 1u);  // round-to-nearest-even
  return (unsigned short)(u >> 16);
}

__device__ __forceinline__ void gload_lds16(const unsigned short* g, unsigned short* l) {
  __builtin_amdgcn_global_load_lds(
      (const __attribute__((address_space(1))) unsigned int*)g,
      (__attribute__((address_space(3))) unsigned int*)l,
      16, 0, 0);
}

// ---------------- fused fp32 -> bf16 convert: 8 elems/thread/iter, 16B stores ----------------
__global__ void cvt_all(const float* __restrict__ x, const float* __restrict__ wq,
                        const float* __restrict__ wp, unsigned short* __restrict__ dst) {
  const int n1 = 4096 * 1024 / 8, n2 = 3072 * 1024 / 8, n3 = 1024 * 1024 / 8;
  int stride = gridDim.x * blockDim.x;
  for (int i = blockIdx.x * blockDim.x + threadIdx.x; i < n1 + n2 + n3; i += stride) {
    const float* s; int j;
    if (i < n1)           { s = x;  j = i; }
    else if (i < n1 + n2) { s = wq; j = i - n1; }
    else                  { s = wp; j = i - n1 - n2; }
    float4 a = ((const float4*)s)[j * 2];
    float4 b = ((const float4*)s)[j * 2 + 1];
    ushort8v o;
    o[0] = f2bf(a.x); o[1] = f2bf(a.y); o[2] = f2bf(a.z); o[3] = f2bf(a.w);
    o[4] = f2bf(b.x); o[5] = f2bf(b.y); o[6] = f2bf(b.z); o[7] = f2bf(b.w);
    ((ushort8v*)dst)[i] = o;
  }
}

// ---------------- 128x128 gemm_bt (PROVEN 2-barrier structure, chunk-XOR) — FROZEN ----------
__device__ __forceinline__ void gemm128_bt(const unsigned short* __restrict__ A,
                                           const unsigned short* __restrict__ Bt,
                                           unsigned short* As, unsigned short* Bs,
                                           int tm, int tn, f32x4 acc[4][4]) {
  const int K = 1024;
  int tid = threadIdx.x;
  int w = tid >> 6, l = tid & 63;
  int wr = w >> 1, wc = w & 1;
  int g = l >> 4, c = l & 15;

  int srow = w * 32 + (l >> 2);
  int skoff = (((l & 3) ^ ((srow >> 1) & 3)) * 8);  // pre-swizzled source k-offset
  const unsigned short* gA = A + (size_t)(tm * 128 + srow) * K + skoff;
  const unsigned short* gB = Bt + (size_t)(tn * 128 + srow) * K + skoff;
  unsigned short* lA = As + (w * 32) * 32;  // wave-uniform LDS base (linear dest)
  unsigned short* lB = Bs + (w * 32) * 32;

  int rx = (c >> 1) & 3;
  int arow = wr * 64 + c;
  int brow = wc * 64 + c;

  for (int k0 = 0; k0 < K; k0 += 32) {
    gload_lds16(gA, lA);
    gload_lds16(gA + 16 * K, lA + 16 * 32);
    gload_lds16(gB, lB);
    gload_lds16(gB + 16 * K, lB + 16 * 32);
    gA += 32; gB += 32;
    __syncthreads();
    bf16x8 af[4], bfr[4];
#pragma unroll
    for (int mi = 0; mi < 4; ++mi)
      af[mi] = *(const bf16x8*)((const char*)As + (arow + mi * 16) * 64 + ((g ^ rx) << 4));
#pragma unroll
    for (int ni = 0; ni < 4; ++ni)
      bfr[ni] = *(const bf16x8*)((const char*)Bs + (brow + ni * 16) * 64 + ((g ^ rx) << 4));
#pragma unroll
    for (int mi = 0; mi < 4; ++mi)
#pragma unroll
      for (int ni = 0; ni < 4; ++ni)
        acc[mi][ni] = __builtin_amdgcn_mfma_f32_16x16x32_bf16(af[mi], bfr[ni], acc[mi][ni], 0, 0, 0);
    __syncthreads();
  }
}

// ---------------- QKV projection: scatter into Q (scaled), K, V^T ----------------
__global__ __launch_bounds__(256) void qkv_gemm(const unsigned short* __restrict__ xb,
                                                const unsigned short* __restrict__ wb,
                                                unsigned short* __restrict__ Qp,
                                                unsigned short* __restrict__ Kp,
                                                unsigned short* __restrict__ Vt) {
  __shared__ unsigned short As[128 * 32];
  __shared__ unsigned short Bs[128 * 32];
  f32x4 acc[4][4];
#pragma unroll
  for (int i = 0; i < 4; ++i)
#pragma unroll
    for (int j = 0; j < 4; ++j) acc[i][j] = f32x4{0.f, 0.f, 0.f, 0.f};
  int id = (blockIdx.x & 7) * 96 + (blockIdx.x >> 3);  // bijective (768 % 8 == 0)
  int tm = id / 24, tn = id % 24;
  gemm128_bt(xb, wb, As, Bs, tm, tn, acc);

  int tid = threadIdx.x;
  int w = tid >> 6, l = tid & 63;
  int wr = w >> 1, wc = w & 1;
  int g = l >> 4, c = l & 15;
  const float QSCALE = 0.125f * 1.44269504088896f;  // hd^-0.5 * log2(e)
#pragma unroll
  for (int mi = 0; mi < 4; ++mi)
#pragma unroll
    for (int ni = 0; ni < 4; ++ni)
#pragma unroll
      for (int r = 0; r < 4; ++r) {
        int row = tm * 128 + wr * 64 + mi * 16 + g * 4 + r;   // 0..4095
        int col = tn * 128 + wc * 64 + ni * 16 + c;           // 0..3071
        int b = row >> 11, seq = row & 2047;
        int t = col >> 10;
        int h = (col >> 6) & 15, d = col & 63;
        size_t bh = (size_t)b * 16 + h;
        float v = acc[mi][ni][r];
        if (t == 0)      Qp[(bh * 2048 + seq) * 64 + d] = f2bf(v * QSCALE);
        else if (t == 1) Kp[(bh * 2048 + seq) * 64 + d] = f2bf(v);
        else             Vt[(bh * 64 + d) * 2048 + seq] = f2bf(v);           // transposed V
      }
}

// ---------------- block-causal flash attention: K-SLICED waves (4x less LDS traffic) ----------
// Wave w owns k-rows [16w,16w+16) of each tile for ALL 64 q-rows: kf = 2 ds_read_b128,
// vf = 4 ds_read_b64 per iter (was 8+16 — all 4 waves previously read identical addrs).
// Q (loop-invariant) hoisted: qf[4][2]. Per-wave partial O / denom over its k-slice;
// one cross-wave LDS reduction after the loop (Ks/Vs reused as f32 scratch).
__global__ __launch_bounds__(256, 3) void attn_fa(const unsigned short* __restrict__ Qp,
                                                  const unsigned short* __restrict__ Kp,
                                                  const unsigned short* __restrict__ Vt,
                                                  unsigned short* __restrict__ attn) {
  __shared__ unsigned short Ks[2][4096];   // [buf][64 seq x 64 d], swizzled; reused as Ored
  __shared__ unsigned short Vs[2][4096];   // [buf][64 d x 64 seq], swizzled; reused as lpred
  int tid = threadIdx.x;
  int w = tid >> 6, l = tid & 63;
  int g = l >> 4, c = l & 15;

  int idx = blockIdx.x;
  int pos = idx >> 3;                    // 0..127
  int qb = 31 - (pos >> 2);              // heavy blocks dispatch first
  int bh = (idx & 7) + 8 * (pos & 3);    // 4 bh per XCD slot (K/V L2 locality)

  const unsigned short* Qbh = Qp + (size_t)bh * 2048 * 64;
  const unsigned short* Kbh = Kp + (size_t)bh * 2048 * 64;
  const unsigned short* Vbh = Vt + (size_t)bh * 64 * 2048;

  int rowA, colA, rowB, colB;
  { int L = tid * 16;         int P = L ^ (((L >> 7) & 7) << 4); rowA = P >> 7; colA = (P & 127) >> 1; }
  { int L = (tid + 256) * 16; int P = L ^ (((L >> 7) & 7) << 4); rowB = P >> 7; colB = (P & 127) >> 1; }
  const unsigned short* gKA = Kbh + rowA * 64 + colA;            // + kb*4096
  const unsigned short* gKB = Kbh + rowB * 64 + colB;
  const unsigned short* gVA = Vbh + (size_t)rowA * 2048 + colA;  // + kb*64
  const unsigned short* gVB = Vbh + (size_t)rowB * 2048 + colB;

#define STAGE(buf, kb)                                              \
  do {                                                              \
    gload_lds16(gKA + (kb) * 4096, &Ks[(buf)][w * 512]);            \
    gload_lds16(gKB + (kb) * 4096, &Ks[(buf)][w * 512 + 2048]);     \
    gload_lds16(gVA + (kb) * 64,  &Vs[(buf)][w * 512]);             \
    gload_lds16(gVB + (kb) * 64,  &Vs[(buf)][w * 512 + 2048]);      \
  } while (0)

  // ALL 64 q-rows hoisted (loop-invariant)
  bf16x8 qf[4][2];
#pragma unroll
  for (int qg = 0; qg < 4; ++qg) {
    size_t qrow = (size_t)qb * 64 + qg * 16 + c;
    qf[qg][0] = *(const bf16x8*)(Qbh + qrow * 64 + 8 * g);
    qf[qg][1] = *(const bf16x8*)(Qbh + qrow * 64 + 32 + 8 * g);
  }

  float lp4[4] = {0.f, 0.f, 0.f, 0.f};  // per-lane k-slice partial denom for q = qg*16+c
  f32x4 o[4][4];                        // [qg][df] partial O over this wave's k-slice
#pragma unroll
  for (int qg = 0; qg < 4; ++qg)
#pragma unroll
    for (int df = 0; df < 4; ++df) o[qg][df] = f32x4{0.f, 0.f, 0.f, 0.f};

  int xorv = c & 7;
  int krow = w * 16 + c;   // this wave's K-slice row (krow&7 == c&7 -> same swizzle)

  int cur = 0;
  STAGE(0, 0);
  __syncthreads();
  for (int kb = 0; kb <= qb; ++kb) {
    if (kb < qb) STAGE(1 - cur, kb + 1);

    const char* Kb = (const char*)&Ks[cur][0];
    const char* Vb = (const char*)&Vs[cur][0];
    // K fragment: only this wave's 16 k-rows (2 reads, was 8)
    bf16x8 kf0 = *(const bf16x8*)(Kb + krow * 128 + (((0 * 4 + g) ^ xorv) * 16));
    bf16x8 kf1 = *(const bf16x8*)(Kb + krow * 128 + (((1 * 4 + g) ^ xorv) * 16));
    // V fragments: only this wave's 16 seq rows (4 b64 reads, was 16)
    u32x2 vf[4];
#pragma unroll
    for (int df = 0; df < 4; ++df)
      vf[df] = *(const u32x2*)(Vb + (df * 16 + c) * 128 + (((2 * w + (g >> 1)) ^ xorv) * 16) + 8 * (g & 1));
    // swapped QK^T per q-group; exp2; pack: lane(g,c) holds P[q=qg*16+c][k=16w+4g+j]
    u32x2 pa[4];
#pragma unroll
    for (int qg = 0; qg < 4; ++qg) {
      f32x4 s4 = f32x4{0.f, 0.f, 0.f, 0.f};
      s4 = __builtin_amdgcn_mfma_f32_16x16x32_bf16(kf0, qf[qg][0], s4, 0, 0, 0);
      s4 = __builtin_amdgcn_mfma_f32_16x16x32_bf16(kf1, qf[qg][1], s4, 0, 0, 0);
      float p0 = __builtin_amdgcn_exp2f(s4[0]);
      float p1 = __builtin_amdgcn_exp2f(s4[1]);
      float p2 = __builtin_amdgcn_exp2f(s4[2]);
      float p3 = __builtin_amdgcn_exp2f(s4[3]);
      lp4[qg] += (p0 + p1) + (p2 + p3);
      unsigned int w0, w1;
      asm("v_cvt_pk_bf16_f32 %0, %1, %2" : "=v"(w0) : "v"(p0), "v"(p1));
      asm("v_cvt_pk_bf16_f32 %0, %1, %2" : "=v"(w1) : "v"(p2), "v"(p3));
      pa[qg][0] = w0; pa[qg][1] = w1;
    }
    // PV over this k-slice: 16 independent x16 MFMAs
#pragma unroll
    for (int qg = 0; qg < 4; ++qg)
#pragma unroll
      for (int df = 0; df < 4; ++df)
        asm("v_mfma_f32_16x16x16_bf16 %0, %1, %2, %0"
            : "+v"(o[qg][df]) : "v"(pa[qg]), "v"(vf[df]));
    __syncthreads();
    cur ^= 1;
  }
#undef STAGE

  // ---- cross-wave reduction (Ks/Vs reused; loop's final barrier already passed) ----
  float* Ored  = (float*)&Ks[0][0];   // [64 q][64 d] f32 = 16KB (exactly Ks)
  float* lpred = (float*)&Vs[0][0];   // [4 w][64 q] f32 = 1KB

  // denom: sum over g within wave (lanes share c), store per (w, q)
  float lpw[4];
#pragma unroll
  for (int qg = 0; qg < 4; ++qg) {
    float v = lp4[qg];
    v += __shfl_xor(v, 16);
    v += __shfl_xor(v, 32);
    lpw[qg] = v;
  }
  if (g == 0) {
#pragma unroll
    for (int qg = 0; qg < 4; ++qg) lpred[w * 64 + qg * 16 + c] = lpw[qg];
  }
  // O: serial RMW rounds; lane(g,c) holds o[qg][df][r] = O[qg*16+4g+r][df*16+c]
  for (int ww = 0; ww < 4; ++ww) {
    if (w == ww) {
#pragma unroll
      for (int qg = 0; qg < 4; ++qg)
#pragma unroll
        for (int df = 0; df < 4; ++df)
#pragma unroll
          for (int r = 0; r < 4; ++r) {
            int q = qg * 16 + 4 * g + r, d = df * 16 + c;
            if (ww == 0) Ored[q * 64 + d] = o[qg][df][r];
            else         Ored[q * 64 + d] += o[qg][df][r];
          }
    }
    __syncthreads();
  }

  // epilogue: rows q = w*16 + g*4 + r (same mapping as proven round-9 epilogue)
  float inv[4];
#pragma unroll
  for (int r = 0; r < 4; ++r) {
    int q = w * 16 + g * 4 + r;
    float s = (lpred[q] + lpred[64 + q]) + (lpred[128 + q] + lpred[192 + q]);
    inv[r] = __builtin_amdgcn_rcpf(s);
  }
  int b = bh >> 4, h = bh & 15;
#pragma unroll
  for (int df = 0; df < 4; ++df)
#pragma unroll
    for (int r = 0; r < 4; ++r) {
      int q = w * 16 + g * 4 + r;
      int row = qb * 64 + q;
      int colc = h * 64 + df * 16 + c;
      attn[((size_t)b * 2048 + row) * 1024 + colc] = f2bf(Ored[q * 64 + df * 16 + c] * inv[r]);
    }
}

// ---------------- output projection + bias (fp32 out) ----------------
__global__ __launch_bounds__(256) void proj_gemm(const unsigned short* __restrict__ attn,
                                                 const unsigned short* __restrict__ wpb,
                                                 const float* __restrict__ bias,
                                                 float* __restrict__ out) {
  __shared__ unsigned short As[128 * 32];
  __shared__ unsigned short Bs[128 * 32];
  f32x4 acc[4][4];
#pragma unroll
  for (int i = 0; i < 4; ++i)
#pragma unroll
    for (int j = 0; j < 4; ++j) acc[i][j] = f32x4{0.f, 0.f, 0.f, 0.f};
  int id = (blockIdx.x & 7) * 32 + (blockIdx.x >> 3);  // bijective (256 % 8 == 0)
  int tm = id / 8, tn = id % 8;
  gemm128_bt(attn, wpb, As, Bs, tm, tn, acc);

  int tid = threadIdx.x;
  int w = tid >> 6, l = tid & 63;
  int wr = w >> 1, wc = w & 1;
  int g = l >> 4, c = l & 15;
#pragma unroll
  for (int mi = 0; mi < 4; ++mi)
#pragma unroll
    for (int ni = 0; ni < 4; ++ni)
#pragma unroll
      for (int r = 0; r < 4; ++r) {
        int row = tm * 128 + wr * 64 + mi * 16 + g * 4 + r;
        int col = tn * 128 + wc * 64 + ni * 16 + c;
        out[(size_t)row * 1024 + col] = acc[mi][ni][r] + bias[col];
      }
}

extern "C" void kernel_launch(void* const* d_in, const int* in_sizes, int n_in,
                              void* d_out, int out_size, void* d_ws, size_t ws_size,
                              hipStream_t stream) {
  (void)in_sizes; (void)n_in; (void)out_size; (void)ws_size;
  const float* x      = (const float*)d_in[0];  // [2,2048,1024]
  const float* w_qkv  = (const float*)d_in[1];  // [3072,1024]
  const float* w_proj = (const float*)d_in[2];  // [1024,1024]
  const float* b_proj = (const float*)d_in[3];  // [1024]
  float* out = (float*)d_out;

  unsigned short* xb    = (unsigned short*)d_ws;          // 4096*1024
  unsigned short* wqkvb = xb + 4096 * 1024;               // 3072*1024
  unsigned short* wpb   = wqkvb + 3072 * 1024;            // 1024*1024
  unsigned short* Qp    = wpb + 1024 * 1024;              // 32*2048*64
  unsigned short* Kp    = Qp + 32 * 2048 * 64;            // 32*2048*64
  unsigned short* Vt    = Kp + 32 * 2048 * 64;            // 32*64*2048
  unsigned short* attn  = Vt + 32 * 64 * 2048;            // 4096*1024

  cvt_all<<<1024, 256, 0, stream>>>(x, w_qkv, w_proj, xb);
  qkv_gemm<<<768, 256, 0, stream>>>(xb, wqkvb, Qp, Kp, Vt);
  attn_fa<<<1024, 256, 0, stream>>>(Qp, Kp, Vt, attn);
  proj_gemm<<<256, 256, 0, stream>>>(attn, wpb, b_proj, out);
}